// Round 1
// baseline (868.368 us; speedup 1.0000x reference)
//
#include <hip/hip_runtime.h>

#define N_DIS 25000
#define N_MIR 25000
#define NN    50000
#define E_NUM 600000
#define EMB   128

// GEMM tiling
#define BM 64
#define KC 64

// bf16 <-> f32 via bit ops (no hip_bf16.h; no bf16 types in any kernel signature)
__device__ __forceinline__ float us2f(unsigned short u) {
    return __uint_as_float(((unsigned)u) << 16);
}
__device__ __forceinline__ unsigned short f2us(float f) {
    unsigned u = __float_as_uint(f);
    unsigned r = ((u >> 16) & 1u) + 0x7FFFu;  // round-to-nearest-even
    u += r;
    return (unsigned short)(u >> 16);
}
// Load element i of a float tensor stored as bf16 (isbf) or f32.
__device__ __forceinline__ float loadf(const void* p, size_t i, bool isbf) {
    if (isbf) return us2f(((const unsigned short*)p)[i]);
    return ((const float*)p)[i];
}

// ---------------- init: zero counts + flag ----------------
__global__ __launch_bounds__(256) void gs_zero(int* counts, int* flags) {
    int i = blockIdx.x * blockDim.x + threadIdx.x;
    if (i < NN) counts[i] = 0;
    if (i < 8) flags[i] = 0;
}

// set flag to a known value (host-determined dtype)
__global__ __launch_bounds__(64) void gs_setflag(int* flags, int v) {
    if (threadIdx.x == 0) flags[0] = v;
}

// dtype probe: bf16 data -> low-16 exponent near 127 (plausible w.p. ~0.99);
// f32 data -> low 16 bits are mantissa junk (plausible w.p. ~0.07). flags[0] += count.
__global__ __launch_bounds__(256) void gs_probe(const void* x, int* flags) {
    const unsigned* u = (const unsigned*)x;
    unsigned w = u[threadIdx.x];
    int e = (int)((w >> 7) & 0xFF);
    if (e >= 118 && e <= 135) atomicAdd(&flags[0], 1);
}

// ---------------- CSR build ----------------
__global__ __launch_bounds__(256) void gs_count(const int* dst, int* counts) {
    int e = blockIdx.x * blockDim.x + threadIdx.x;
    if (e < E_NUM) {
        unsigned d = (unsigned)dst[e];
        if (d < (unsigned)NN) atomicAdd(&counts[d], 1);
    }
}

__global__ __launch_bounds__(256) void gs_scan1(const int* counts, int* row_start, int* bsums) {
    __shared__ int tsum[256];
    const int t = threadIdx.x;
    const int base = blockIdx.x * 1024 + t * 4;
    int v0 = (base + 0 < NN) ? counts[base + 0] : 0;
    int v1 = (base + 1 < NN) ? counts[base + 1] : 0;
    int v2 = (base + 2 < NN) ? counts[base + 2] : 0;
    int v3 = (base + 3 < NN) ? counts[base + 3] : 0;
    int s = v0 + v1 + v2 + v3;
    tsum[t] = s;
    __syncthreads();
    for (int off = 1; off < 256; off <<= 1) {
        int xv = 0;
        if (t >= off) xv = tsum[t - off];
        __syncthreads();
        tsum[t] += xv;
        __syncthreads();
    }
    int excl = tsum[t] - s;
    if (base + 0 < NN) row_start[base + 0] = excl;
    excl += v0;
    if (base + 1 < NN) row_start[base + 1] = excl;
    excl += v1;
    if (base + 2 < NN) row_start[base + 2] = excl;
    excl += v2;
    if (base + 3 < NN) row_start[base + 3] = excl;
    if (t == 255) bsums[blockIdx.x] = tsum[255];
}

__global__ __launch_bounds__(64) void gs_scan2(int* bsums, int* row_start, int nb) {
    if (threadIdx.x == 0) {
        int run = 0;
        for (int i = 0; i < nb; ++i) {
            int v = bsums[i];
            bsums[i] = run;
            run += v;
        }
        row_start[NN] = run;
    }
}

__global__ __launch_bounds__(256) void gs_scan3(int* row_start, int* cursor, const int* bsums) {
    const int t = threadIdx.x;
    const int base = blockIdx.x * 1024 + t * 4;
    const int add = bsums[blockIdx.x];
    for (int i = 0; i < 4; ++i) {
        int idx = base + i;
        if (idx < NN) {
            int v = row_start[idx] + add;
            row_start[idx] = v;
            cursor[idx] = v;
        }
    }
}

__global__ __launch_bounds__(256) void gs_scatter(const int* src, const int* dst, int* cursor,
                                                  int* eidx) {
    int e = blockIdx.x * blockDim.x + threadIdx.x;
    if (e < E_NUM) {
        unsigned d = (unsigned)dst[e];
        unsigned sv = (unsigned)src[e];
        if (d < (unsigned)NN && sv < (unsigned)NN) {
            int p = atomicAdd(&cursor[d], 1);
            eidx[p] = (int)sv;
        }
    }
}

// ---------------- mean aggregation: agg[n] = mean_{e in CSR[n]} x[eidx[e]] ----------------
// 8 rows per block; 32 lanes per row, float4 per lane (128 cols).
__global__ __launch_bounds__(256) void gs_agg(const float* __restrict__ x,
                                              const int* __restrict__ row_start,
                                              const int* __restrict__ eidx,
                                              float* __restrict__ agg) {
    const int t = threadIdx.x;
    const int row = blockIdx.x * 8 + (t >> 5);
    const int tc = (t & 31) * 4;
    if (row >= NN) return;
    const int s0 = row_start[row];
    const int s1 = row_start[row + 1];
    float a0x = 0.f, a0y = 0.f, a0z = 0.f, a0w = 0.f;
    float a1x = 0.f, a1y = 0.f, a1z = 0.f, a1w = 0.f;
    int e = s0;
    for (; e + 1 < s1; e += 2) {
        int sa = eidx[e];
        int sb = eidx[e + 1];
        float4 va = *(const float4*)&x[(size_t)sa * EMB + tc];
        float4 vb = *(const float4*)&x[(size_t)sb * EMB + tc];
        a0x += va.x; a0y += va.y; a0z += va.z; a0w += va.w;
        a1x += vb.x; a1y += vb.y; a1z += vb.z; a1w += vb.w;
    }
    if (e < s1) {
        int sa = eidx[e];
        float4 va = *(const float4*)&x[(size_t)sa * EMB + tc];
        a0x += va.x; a0y += va.y; a0z += va.z; a0w += va.w;
    }
    float inv = (s1 > s0) ? 1.f / (float)(s1 - s0) : 0.f;
    float4 o;
    o.x = (a0x + a1x) * inv;
    o.y = (a0y + a1y) * inv;
    o.z = (a0z + a1z) * inv;
    o.w = (a0w + a1w) * inv;
    *(float4*)&agg[(size_t)row * EMB + tc] = o;
}

// ---------------- tiled f32 GEMM: out[M,128] = [relu](X1@W1 + (X2@W2) + b) ----------------
// X1: [M,K1] f32 or bf16 (bf16 only when x1_dyn && flags say bf16). W1: [K1,128] input dtype.
// X2: optional [M,128] f32 (aggregation), W2: [128,128] input dtype.
// BM=64 rows/block, 256 threads, each thread: 8 rows x 4 cols (acc[8][4]).
__global__ __launch_bounds__(256) void gs_gemm(const void* __restrict__ X1, int K1,
                                               const void* __restrict__ W1,
                                               const float* __restrict__ X2,
                                               const void* __restrict__ W2,
                                               const void* __restrict__ bias,
                                               const int* __restrict__ flags,
                                               float* __restrict__ out, int M, int x1_dyn,
                                               int do_relu) {
    __shared__ __align__(16) float xs[BM][KC];   // 16 KB
    __shared__ __align__(16) float ws[KC][EMB];  // 32 KB
    const bool isbf = flags[0] > 128;
    const bool x1bf = (x1_dyn != 0) && isbf;
    const int t = threadIdx.x;
    const int r0 = blockIdx.x * BM;
    const int c4 = (t & 31) * 4;  // this thread's 4 output cols
    const int rg = t >> 5;        // row group: rows rg*8 .. rg*8+7

    float acc[8][4];
#pragma unroll
    for (int r = 0; r < 8; ++r)
#pragma unroll
        for (int j = 0; j < 4; ++j) acc[r][j] = 0.f;

    const int nch1 = (K1 + KC - 1) / KC;
    const int totch = nch1 + (X2 ? 2 : 0);

    for (int ch = 0; ch < totch; ++ch) {
        const void* X;
        const void* W;
        int k0, K;
        bool xbf;
        if (ch < nch1) {
            X = X1; W = W1; k0 = ch * KC; K = K1; xbf = x1bf;
        } else {
            X = (const void*)X2; W = W2; k0 = (ch - nch1) * KC; K = EMB; xbf = false;
        }
        __syncthreads();  // previous tile fully consumed before overwrite
        // stage X tile: BM x KC, zero-padded outside [M,K)
        for (int i = t; i < BM * KC; i += 256) {
            int r = i >> 6;
            int k = i & (KC - 1);
            int gr = r0 + r, gk = k0 + k;
            float v = 0.f;
            if (gr < M && gk < K)
                v = xbf ? us2f(((const unsigned short*)X)[(size_t)gr * K + gk])
                        : ((const float*)X)[(size_t)gr * K + gk];
            xs[r][k] = v;
        }
        // stage W tile: KC x 128, zero-padded for k >= K
        for (int i = t; i < KC * EMB; i += 256) {
            int k = i >> 7;
            int c = i & 127;
            int gk = k0 + k;
            ws[k][c] = (gk < K) ? loadf(W, (size_t)gk * (size_t)EMB + c, isbf) : 0.f;
        }
        __syncthreads();
        // compute: 16 k4-steps of 4 k each
#pragma unroll 4
        for (int k4 = 0; k4 < KC / 4; ++k4) {
            float4 xv[8];
#pragma unroll
            for (int r = 0; r < 8; ++r)
                xv[r] = *(const float4*)&xs[rg * 8 + r][k4 * 4];
#pragma unroll
            for (int kk = 0; kk < 4; ++kk) {
                float4 wv = *(const float4*)&ws[k4 * 4 + kk][c4];
#pragma unroll
                for (int r = 0; r < 8; ++r) {
                    float xr = (kk == 0) ? xv[r].x
                             : (kk == 1) ? xv[r].y
                             : (kk == 2) ? xv[r].z
                                         : xv[r].w;
                    acc[r][0] = fmaf(xr, wv.x, acc[r][0]);
                    acc[r][1] = fmaf(xr, wv.y, acc[r][1]);
                    acc[r][2] = fmaf(xr, wv.z, acc[r][2]);
                    acc[r][3] = fmaf(xr, wv.w, acc[r][3]);
                }
            }
        }
    }

    // epilogue: + bias, optional relu, float4 store
    float b0 = loadf(bias, c4 + 0, isbf);
    float b1 = loadf(bias, c4 + 1, isbf);
    float b2 = loadf(bias, c4 + 2, isbf);
    float b3 = loadf(bias, c4 + 3, isbf);
#pragma unroll
    for (int r = 0; r < 8; ++r) {
        int row = r0 + rg * 8 + r;
        if (row < M) {
            float4 o;
            o.x = acc[r][0] + b0;
            o.y = acc[r][1] + b1;
            o.z = acc[r][2] + b2;
            o.w = acc[r][3] + b3;
            if (do_relu) {
                o.x = o.x > 0.f ? o.x : 0.f;
                o.y = o.y > 0.f ? o.y : 0.f;
                o.z = o.z > 0.f ? o.z : 0.f;
                o.w = o.w > 0.f ? o.w : 0.f;
            }
            *(float4*)&out[(size_t)row * EMB + c4] = o;
        }
    }
}

extern "C" __attribute__((visibility("default"))) void kernel_launch(
    void* const* d_in, const int* in_sizes, int n_in, void* d_out, int out_size, void* d_ws,
    size_t ws_size, hipStream_t stream) {
    // ---- ordering + dtype from in_sizes[0] (d_features in dict order, W_d if sorted) ----
    // dict order: d_features -> 9,575,000 elements. sorted-key order: W_d -> 49,024 elements.
    int iDF = 0, iMF = 1, iSRC = 2, iDST = 3, iWD = 4, iBD = 5, iWM = 6, iBM = 7;
    int iWS1 = 8, iWN1 = 9, iB1 = 10, iWS2 = 11, iWN2 = 12, iB2 = 13;
    long u0 = in_sizes ? (long)in_sizes[0] : 9575000L;
    int dt = -1;  // -1 unknown (probe), 0 f32, 1 bf16
    if (u0 == 49024L || u0 == 98048L || u0 == 196096L) {
        iWD = 0; iWM = 1; iWN1 = 2; iWN2 = 3; iWS1 = 4; iWS2 = 5;
        iB1 = 6; iB2 = 7; iBD = 8; iBM = 9; iDF = 10; iDST = 11; iMF = 12; iSRC = 13;
        if (u0 == 98048L) dt = 1;
        else if (u0 == 196096L) dt = 0;
    } else {
        if (u0 == 19150000L) dt = 1;       // bytes, bf16
        else if (u0 == 38300000L) dt = 0;  // bytes, f32
        // 9,575,000 (elements): dtype unknown -> device probe
    }
    const void* d_features = d_in[iDF];
    const void* m_features = d_in[iMF];
    const int* src = (const int*)d_in[iSRC];
    const int* dst = (const int*)d_in[iDST];
    const void* W_d = d_in[iWD];
    const void* b_d = d_in[iBD];
    const void* W_m = d_in[iWM];
    const void* b_m = d_in[iBM];
    const void* W_self1 = d_in[iWS1];
    const void* W_neigh1 = d_in[iWN1];
    const void* b1 = d_in[iB1];
    const void* W_self2 = d_in[iWS2];
    const void* W_neigh2 = d_in[iWN2];
    const void* b2v = d_in[iB2];

    // ---- workspace layout (unchanged footprint, ~54.2 MB) ----
    char* w = (char*)d_ws;
    int* flags = (int*)(w + 0);            //        64 B
    int* counts = (int*)(w + 64);          //   200,000 B
    int* row_start = (int*)(w + 200064);   //   200,004 B (pad to 400128)
    int* cursor = (int*)(w + 400128);      //   200,000 B
    int* bsums = (int*)(w + 600128);       //       256 B
    int* eidx = (int*)(w + 600384);        // 2,400,000 B (pad to 3000448)
    float* hF = (float*)(w + 3000448);     // 25,600,000 B
    float* h1F = (float*)(w + 28600448);   // 25,600,000 B -> ends 54,200,448
    // agg scratch: layer1 agg lives in d_out (f32 [NN,128], written before final use);
    // layer2 agg reuses hF (dead after layer-1 GEMM reads it).

    const int NB_SCAN = (NN + 1023) / 1024;  // 49
    const int EB = (E_NUM + 255) / 256;      // 2344
    const int ZB = (NN + 255) / 256;         // 196

    // init + dtype resolution (flags[0] > 128 => bf16)
    hipLaunchKernelGGL(gs_zero, dim3(ZB), dim3(256), 0, stream, counts, flags);
    if (dt == 1)
        hipLaunchKernelGGL(gs_setflag, dim3(1), dim3(64), 0, stream, flags, 1000);
    else if (dt == 0)
        hipLaunchKernelGGL(gs_setflag, dim3(1), dim3(64), 0, stream, flags, 0);
    else
        hipLaunchKernelGGL(gs_probe, dim3(1), dim3(256), 0, stream, d_features, flags);

    // CSR build (dims hardcoded)
    hipLaunchKernelGGL(gs_count, dim3(EB), dim3(256), 0, stream, dst, counts);
    hipLaunchKernelGGL(gs_scan1, dim3(NB_SCAN), dim3(256), 0, stream, counts, row_start, bsums);
    hipLaunchKernelGGL(gs_scan2, dim3(1), dim3(64), 0, stream, bsums, row_start, NB_SCAN);
    hipLaunchKernelGGL(gs_scan3, dim3(NB_SCAN), dim3(256), 0, stream, row_start, cursor, bsums);
    hipLaunchKernelGGL(gs_scatter, dim3(EB), dim3(256), 0, stream, src, dst, cursor, eidx);

    // per-type embedding projection -> hF (f32), tiled GEMM
    const int PB = (N_DIS + BM - 1) / BM;  // 391
    hipLaunchKernelGGL(gs_gemm, dim3(PB), dim3(256), 0, stream, d_features, 383, W_d,
                       (const float*)nullptr, (const void*)nullptr, b_d, flags, hF, N_DIS, 1, 0);
    hipLaunchKernelGGL(gs_gemm, dim3(PB), dim3(256), 0, stream, m_features, 495, W_m,
                       (const float*)nullptr, (const void*)nullptr, b_m, flags,
                       hF + (size_t)N_DIS * EMB, N_MIR, 1, 0);

    const int AB = NN / 8;                // 6250
    const int GB = (NN + BM - 1) / BM;    // 782

    // layer 1: agg(hF) -> d_out scratch; out = relu(hF@Ws1 + agg@Wn1 + b1) -> h1F
    hipLaunchKernelGGL(gs_agg, dim3(AB), dim3(256), 0, stream, hF, row_start, eidx,
                       (float*)d_out);
    hipLaunchKernelGGL(gs_gemm, dim3(GB), dim3(256), 0, stream, (const void*)hF, EMB, W_self1,
                       (const float*)d_out, W_neigh1, b1, flags, h1F, NN, 0, 1);

    // layer 2: agg(h1F) -> hF scratch; out = h1F@Ws2 + agg@Wn2 + b2 -> d_out (f32)
    hipLaunchKernelGGL(gs_agg, dim3(AB), dim3(256), 0, stream, h1F, row_start, eidx, hF);
    hipLaunchKernelGGL(gs_gemm, dim3(GB), dim3(256), 0, stream, (const void*)h1F, EMB, W_self2,
                       (const float*)hF, W_neigh2, b2v, flags, (float*)d_out, NN, 0, 0);
}

// Round 2
// 543.812 us; speedup vs baseline: 1.5968x; 1.5968x over previous
//
#include <hip/hip_runtime.h>

#define N_DIS 25000
#define N_MIR 25000
#define NN    50000
#define E_NUM 600000
#define EMB   128

// GEMM tiling: 128 rows/block, 512 threads, K-chunk 32, each thread 8 rows x 4 cols.
#define BMG 128
#define KCG 32
#define TG  512

// bf16 -> f32 via bit ops (no hip_bf16.h; no bf16 types in any kernel signature)
__device__ __forceinline__ float us2f(unsigned short u) {
    return __uint_as_float(((unsigned)u) << 16);
}
// Load element i of a float tensor stored as bf16 (isbf) or f32.
__device__ __forceinline__ float loadf(const void* p, size_t i, bool isbf) {
    if (isbf) return us2f(((const unsigned short*)p)[i]);
    return ((const float*)p)[i];
}

// ---------------- init: zero counts + flag ----------------
__global__ __launch_bounds__(256) void gs_zero(int* counts, int* flags) {
    int i = blockIdx.x * blockDim.x + threadIdx.x;
    if (i < NN) counts[i] = 0;
    if (i < 8) flags[i] = 0;
}

__global__ __launch_bounds__(64) void gs_setflag(int* flags, int v) {
    if (threadIdx.x == 0) flags[0] = v;
}

// dtype probe: bf16 data -> low-16 exponent near 127 (plausible w.p. ~0.99);
// f32 data -> low 16 bits are mantissa junk (plausible w.p. ~0.07). flags[0] += count.
__global__ __launch_bounds__(256) void gs_probe(const void* x, int* flags) {
    const unsigned* u = (const unsigned*)x;
    unsigned w = u[threadIdx.x];
    int e = (int)((w >> 7) & 0xFF);
    if (e >= 118 && e <= 135) atomicAdd(&flags[0], 1);
}

// ---------------- CSR build ----------------
__global__ __launch_bounds__(256) void gs_count(const int* dst, int* counts) {
    int e = blockIdx.x * blockDim.x + threadIdx.x;
    if (e < E_NUM) {
        unsigned d = (unsigned)dst[e];
        if (d < (unsigned)NN) atomicAdd(&counts[d], 1);
    }
}

__global__ __launch_bounds__(256) void gs_scan1(const int* counts, int* row_start, int* bsums) {
    __shared__ int tsum[256];
    const int t = threadIdx.x;
    const int base = blockIdx.x * 1024 + t * 4;
    int v0 = (base + 0 < NN) ? counts[base + 0] : 0;
    int v1 = (base + 1 < NN) ? counts[base + 1] : 0;
    int v2 = (base + 2 < NN) ? counts[base + 2] : 0;
    int v3 = (base + 3 < NN) ? counts[base + 3] : 0;
    int s = v0 + v1 + v2 + v3;
    tsum[t] = s;
    __syncthreads();
    for (int off = 1; off < 256; off <<= 1) {
        int xv = 0;
        if (t >= off) xv = tsum[t - off];
        __syncthreads();
        tsum[t] += xv;
        __syncthreads();
    }
    int excl = tsum[t] - s;
    if (base + 0 < NN) row_start[base + 0] = excl;
    excl += v0;
    if (base + 1 < NN) row_start[base + 1] = excl;
    excl += v1;
    if (base + 2 < NN) row_start[base + 2] = excl;
    excl += v2;
    if (base + 3 < NN) row_start[base + 3] = excl;
    if (t == 255) bsums[blockIdx.x] = tsum[255];
}

__global__ __launch_bounds__(64) void gs_scan2(int* bsums, int* row_start, int nb) {
    if (threadIdx.x == 0) {
        int run = 0;
        for (int i = 0; i < nb; ++i) {
            int v = bsums[i];
            bsums[i] = run;
            run += v;
        }
        row_start[NN] = run;
    }
}

__global__ __launch_bounds__(256) void gs_scan3(int* row_start, int* cursor, const int* bsums) {
    const int t = threadIdx.x;
    const int base = blockIdx.x * 1024 + t * 4;
    const int add = bsums[blockIdx.x];
    for (int i = 0; i < 4; ++i) {
        int idx = base + i;
        if (idx < NN) {
            int v = row_start[idx] + add;
            row_start[idx] = v;
            cursor[idx] = v;
        }
    }
}

__global__ __launch_bounds__(256) void gs_scatter(const int* src, const int* dst, int* cursor,
                                                  int* eidx) {
    int e = blockIdx.x * blockDim.x + threadIdx.x;
    if (e < E_NUM) {
        unsigned d = (unsigned)dst[e];
        unsigned sv = (unsigned)src[e];
        if (d < (unsigned)NN && sv < (unsigned)NN) {
            int p = atomicAdd(&cursor[d], 1);
            eidx[p] = (int)sv;
        }
    }
}

// ---------------- mean aggregation: agg[n] = mean_{e in CSR[n]} x[eidx[e]] ----------------
// 8 rows per block; 32 lanes per row, float4 per lane (128 cols).
__global__ __launch_bounds__(256) void gs_agg(const float* __restrict__ x,
                                              const int* __restrict__ row_start,
                                              const int* __restrict__ eidx,
                                              float* __restrict__ agg) {
    const int t = threadIdx.x;
    const int row = blockIdx.x * 8 + (t >> 5);
    const int tc = (t & 31) * 4;
    if (row >= NN) return;
    const int s0 = row_start[row];
    const int s1 = row_start[row + 1];
    float a0x = 0.f, a0y = 0.f, a0z = 0.f, a0w = 0.f;
    float a1x = 0.f, a1y = 0.f, a1z = 0.f, a1w = 0.f;
    int e = s0;
    for (; e + 1 < s1; e += 2) {
        int sa = eidx[e];
        int sb = eidx[e + 1];
        float4 va = *(const float4*)&x[(size_t)sa * EMB + tc];
        float4 vb = *(const float4*)&x[(size_t)sb * EMB + tc];
        a0x += va.x; a0y += va.y; a0z += va.z; a0w += va.w;
        a1x += vb.x; a1y += vb.y; a1z += vb.z; a1w += vb.w;
    }
    if (e < s1) {
        int sa = eidx[e];
        float4 va = *(const float4*)&x[(size_t)sa * EMB + tc];
        a0x += va.x; a0y += va.y; a0z += va.z; a0w += va.w;
    }
    float inv = (s1 > s0) ? 1.f / (float)(s1 - s0) : 0.f;
    float4 o;
    o.x = (a0x + a1x) * inv;
    o.y = (a0y + a1y) * inv;
    o.z = (a0z + a1z) * inv;
    o.w = (a0w + a1w) * inv;
    *(float4*)&agg[(size_t)row * EMB + tc] = o;
}

// ---------------- tiled f32 GEMM, block-split over two problem sides ----------------
// Side A (blocks [0,splitB)): out[r,:] = act(Xa[r,:Ka]@Wa + (X2@W2 if X2) + ba), r in [0,Ma)
// Side B (blocks [splitB,..)): out[Ma+r,:] = act(Xb[r,:Kb]@Wb + bb), r in [0,Mb)
// X2 rows are indexed by global output row (layer mode only; layer uses side A only).
__global__ __launch_bounds__(TG, 4) void gs_gemm(
    const void* __restrict__ Xa, int Ka, const void* __restrict__ Wa, const void* __restrict__ ba,
    const void* __restrict__ Xb, int Kb, const void* __restrict__ Wb, const void* __restrict__ bb,
    int splitB, int Ma, int Mb,
    const float* __restrict__ X2, const void* __restrict__ W2,
    const int* __restrict__ flags, float* __restrict__ out, int x1_dyn, int do_relu) {
    __shared__ __align__(16) float xs[BMG][KCG];   // 16 KB
    __shared__ __align__(16) float ws[KCG][EMB];   // 16 KB
    const bool isbf = flags[0] > 128;
    const int t = threadIdx.x;
    const bool sideB = (int)blockIdx.x >= splitB;
    const void* X1 = sideB ? Xb : Xa;
    const void* W1 = sideB ? Wb : Wa;
    const void* bias = sideB ? bb : ba;
    const int K1 = sideB ? Kb : Ka;
    const int M = sideB ? Mb : Ma;
    const int r0 = (sideB ? ((int)blockIdx.x - splitB) : (int)blockIdx.x) * BMG;
    float* outb = out + (sideB ? (size_t)Ma * EMB : 0);

    const int c4 = (t & 31) * 4;  // 4 output cols
    const int rg = t >> 5;        // row group: rows rg*8 .. rg*8+7

    float acc[8][4];
#pragma unroll
    for (int r = 0; r < 8; ++r)
#pragma unroll
        for (int j = 0; j < 4; ++j) acc[r][j] = 0.f;

    const int nch1 = (K1 + KCG - 1) / KCG;
    const int totch = nch1 + (X2 ? (EMB / KCG) : 0);

    for (int ch = 0; ch < totch; ++ch) {
        const void* X;
        const void* W;
        int k0, K;
        bool xbf;
        if (ch < nch1) {
            X = X1; W = W1; k0 = ch * KCG; K = K1; xbf = (x1_dyn != 0) && isbf;
        } else {
            X = (const void*)X2; W = W2; k0 = (ch - nch1) * KCG; K = EMB; xbf = false;
        }
        __syncthreads();  // previous tile fully consumed before overwrite

        // ---- stage X tile: BMG x KCG ----
        const bool vecX = (!xbf) && ((K & 31) == 0);  // aligned rows, no K tail
        if (vecX) {
            const float* Xf = (const float*)X;
#pragma unroll
            for (int i = t; i < BMG * KCG / 4; i += TG) {  // 2 iters
                int r = i >> 3;
                int kq = (i & 7) << 2;
                int gr = r0 + r;
                float4 v = make_float4(0.f, 0.f, 0.f, 0.f);
                if (gr < M) v = *(const float4*)&Xf[(size_t)gr * K + k0 + kq];
                *(float4*)&xs[r][kq] = v;
            }
        } else {
#pragma unroll
            for (int i = t; i < BMG * KCG; i += TG) {  // 8 iters
                int r = i >> 5;
                int k = i & (KCG - 1);
                int gr = r0 + r, gk = k0 + k;
                float v = 0.f;
                if (gr < M && gk < K)
                    v = xbf ? us2f(((const unsigned short*)X)[(size_t)gr * K + gk])
                            : ((const float*)X)[(size_t)gr * K + gk];
                xs[r][k] = v;
            }
        }
        // ---- stage W tile: KCG x 128 (f32 or bf16 input dtype) ----
#pragma unroll
        for (int i = t; i < KCG * EMB / 4; i += TG) {  // 2 iters
            int k = i >> 5;
            int c = (i & 31) << 2;
            int gk = k0 + k;
            float4 v = make_float4(0.f, 0.f, 0.f, 0.f);
            if (gk < K) {
                if (isbf) {
                    uint2 u = *(const uint2*)((const unsigned*)W + (((size_t)gk) << 6) + (c >> 1));
                    v.x = us2f((unsigned short)(u.x & 0xFFFFu));
                    v.y = us2f((unsigned short)(u.x >> 16));
                    v.z = us2f((unsigned short)(u.y & 0xFFFFu));
                    v.w = us2f((unsigned short)(u.y >> 16));
                } else {
                    v = *(const float4*)&((const float*)W)[((size_t)gk << 7) + c];
                }
            }
            *(float4*)&ws[k][c] = v;
        }
        __syncthreads();

        // ---- compute: 8 k4-steps of 4 k each ----
#pragma unroll 4
        for (int k4 = 0; k4 < KCG / 4; ++k4) {
            float4 xv[8];
#pragma unroll
            for (int r = 0; r < 8; ++r) xv[r] = *(const float4*)&xs[rg * 8 + r][k4 << 2];
#pragma unroll
            for (int kk = 0; kk < 4; ++kk) {
                float4 wv = *(const float4*)&ws[(k4 << 2) + kk][c4];
#pragma unroll
                for (int r = 0; r < 8; ++r) {
                    float xr = (kk == 0) ? xv[r].x
                             : (kk == 1) ? xv[r].y
                             : (kk == 2) ? xv[r].z
                                         : xv[r].w;
                    acc[r][0] = fmaf(xr, wv.x, acc[r][0]);
                    acc[r][1] = fmaf(xr, wv.y, acc[r][1]);
                    acc[r][2] = fmaf(xr, wv.z, acc[r][2]);
                    acc[r][3] = fmaf(xr, wv.w, acc[r][3]);
                }
            }
        }
    }

    // ---- epilogue: + bias, optional relu, float4 store ----
    float b0 = loadf(bias, c4 + 0, isbf);
    float b1 = loadf(bias, c4 + 1, isbf);
    float b2 = loadf(bias, c4 + 2, isbf);
    float b3 = loadf(bias, c4 + 3, isbf);
#pragma unroll
    for (int r = 0; r < 8; ++r) {
        int row = r0 + rg * 8 + r;
        if (row < M) {
            float4 o;
            o.x = acc[r][0] + b0;
            o.y = acc[r][1] + b1;
            o.z = acc[r][2] + b2;
            o.w = acc[r][3] + b3;
            if (do_relu) {
                o.x = o.x > 0.f ? o.x : 0.f;
                o.y = o.y > 0.f ? o.y : 0.f;
                o.z = o.z > 0.f ? o.z : 0.f;
                o.w = o.w > 0.f ? o.w : 0.f;
            }
            *(float4*)&outb[(size_t)row * EMB + c4] = o;
        }
    }
}

extern "C" __attribute__((visibility("default"))) void kernel_launch(
    void* const* d_in, const int* in_sizes, int n_in, void* d_out, int out_size, void* d_ws,
    size_t ws_size, hipStream_t stream) {
    // ---- ordering + dtype from in_sizes[0] (d_features in dict order, W_d if sorted) ----
    int iDF = 0, iMF = 1, iSRC = 2, iDST = 3, iWD = 4, iBD = 5, iWM = 6, iBM = 7;
    int iWS1 = 8, iWN1 = 9, iB1 = 10, iWS2 = 11, iWN2 = 12, iB2 = 13;
    long u0 = in_sizes ? (long)in_sizes[0] : 9575000L;
    int dt = -1;  // -1 unknown (probe), 0 f32, 1 bf16
    if (u0 == 49024L || u0 == 98048L || u0 == 196096L) {
        iWD = 0; iWM = 1; iWN1 = 2; iWN2 = 3; iWS1 = 4; iWS2 = 5;
        iB1 = 6; iB2 = 7; iBD = 8; iBM = 9; iDF = 10; iDST = 11; iMF = 12; iSRC = 13;
        if (u0 == 98048L) dt = 1;
        else if (u0 == 196096L) dt = 0;
    } else {
        if (u0 == 19150000L) dt = 1;       // bytes, bf16
        else if (u0 == 38300000L) dt = 0;  // bytes, f32
    }
    const void* d_features = d_in[iDF];
    const void* m_features = d_in[iMF];
    const int* src = (const int*)d_in[iSRC];
    const int* dst = (const int*)d_in[iDST];
    const void* W_d = d_in[iWD];
    const void* b_d = d_in[iBD];
    const void* W_m = d_in[iWM];
    const void* b_m = d_in[iBM];
    const void* W_self1 = d_in[iWS1];
    const void* W_neigh1 = d_in[iWN1];
    const void* b1 = d_in[iB1];
    const void* W_self2 = d_in[iWS2];
    const void* W_neigh2 = d_in[iWN2];
    const void* b2v = d_in[iB2];

    // ---- workspace layout (unchanged footprint, ~54.2 MB) ----
    char* w = (char*)d_ws;
    int* flags = (int*)(w + 0);            //        64 B
    int* counts = (int*)(w + 64);          //   200,000 B
    int* row_start = (int*)(w + 200064);   //   200,004 B (pad to 400128)
    int* cursor = (int*)(w + 400128);      //   200,000 B
    int* bsums = (int*)(w + 600128);       //       256 B
    int* eidx = (int*)(w + 600384);        // 2,400,000 B (pad to 3000448)
    float* hF = (float*)(w + 3000448);     // 25,600,000 B
    float* h1F = (float*)(w + 28600448);   // 25,600,000 B -> ends 54,200,448
    // agg scratch: layer1 agg -> d_out (overwritten later); layer2 agg -> hF (dead after L1 gemm)

    const int NB_SCAN = (NN + 1023) / 1024;  // 49
    const int EB = (E_NUM + 255) / 256;      // 2344
    const int ZB = (NN + 255) / 256;         // 196

    // init + dtype resolution (flags[0] > 128 => bf16)
    hipLaunchKernelGGL(gs_zero, dim3(ZB), dim3(256), 0, stream, counts, flags);
    if (dt == 1)
        hipLaunchKernelGGL(gs_setflag, dim3(1), dim3(64), 0, stream, flags, 1000);
    else if (dt == 0)
        hipLaunchKernelGGL(gs_setflag, dim3(1), dim3(64), 0, stream, flags, 0);
    else
        hipLaunchKernelGGL(gs_probe, dim3(1), dim3(256), 0, stream, d_features, flags);

    // CSR build
    hipLaunchKernelGGL(gs_count, dim3(EB), dim3(256), 0, stream, dst, counts);
    hipLaunchKernelGGL(gs_scan1, dim3(NB_SCAN), dim3(256), 0, stream, counts, row_start, bsums);
    hipLaunchKernelGGL(gs_scan2, dim3(1), dim3(64), 0, stream, bsums, row_start, NB_SCAN);
    hipLaunchKernelGGL(gs_scan3, dim3(NB_SCAN), dim3(256), 0, stream, row_start, cursor, bsums);
    hipLaunchKernelGGL(gs_scatter, dim3(EB), dim3(256), 0, stream, src, dst, cursor, eidx);

    // both projections in ONE dispatch (block-split): blocks [0,196) disease, [196,392) mirna
    const int PBd = (N_DIS + BMG - 1) / BMG;  // 196
    hipLaunchKernelGGL(gs_gemm, dim3(2 * PBd), dim3(TG), 0, stream,
                       d_features, 383, W_d, b_d,
                       m_features, 495, W_m, b_m,
                       PBd, N_DIS, N_MIR,
                       (const float*)nullptr, (const void*)nullptr,
                       flags, hF, 1, 0);

    const int AB = NN / 8;                 // 6250
    const int GB = (NN + BMG - 1) / BMG;   // 391

    // layer 1: agg(hF) -> d_out scratch; h1F = relu(hF@Ws1 + agg@Wn1 + b1)
    hipLaunchKernelGGL(gs_agg, dim3(AB), dim3(256), 0, stream, hF, row_start, eidx,
                       (float*)d_out);
    hipLaunchKernelGGL(gs_gemm, dim3(GB), dim3(TG), 0, stream,
                       (const void*)hF, EMB, W_self1, b1,
                       (const void*)nullptr, 0, (const void*)nullptr, (const void*)nullptr,
                       GB, NN, 0,
                       (const float*)d_out, W_neigh1,
                       flags, h1F, 0, 1);

    // layer 2: agg(h1F) -> hF scratch; d_out = h1F@Ws2 + agg@Wn2 + b2 (f32)
    hipLaunchKernelGGL(gs_agg, dim3(AB), dim3(256), 0, stream, h1F, row_start, eidx, hF);
    hipLaunchKernelGGL(gs_gemm, dim3(GB), dim3(TG), 0, stream,
                       (const void*)h1F, EMB, W_self2, b2v,
                       (const void*)nullptr, 0, (const void*)nullptr, (const void*)nullptr,
                       GB, NN, 0,
                       (const float*)hF, W_neigh2,
                       flags, (float*)d_out, 0, 0);
}